// Round 2
// baseline (186.411 us; speedup 1.0000x reference)
//
#include <hip/hip_runtime.h>

// SNN spike layer: causal alpha-PSP FIR conv (taps 1..76; srm[0]==0 exactly)
// + sequential refractory threshold scan.
//
// Key structural insight: the conv filters the INPUT spikes (feed-forward);
// only the 10-slot refractory scan is sequential. Previous build ran 1 thread
// per neuron = 1024 waves = exactly 1 wave/SIMD (grid-limited, Occupancy 9.3%,
// VALUBusy 57% -> 43% exposed stall). This build splits the conv across
// 4 threads/neuron (time-quarters 80/80/80/60), stages u in LDS (never HBM),
// and scans on wave 0. 1024 blocks x 256 threads, 77KB LDS -> 2 blocks/CU =
// 8 waves/CU = 2 waves/SIMD of latency hiding.
//
// Bit-exactness: each u[t] still accumulates taps j=1..76 ascending via fmaf
// (identical order to the 177us baseline that scored absmax==0.0); q=0
// pre-window zeros give fmaf(w,0,u)==u; scan step identical.

#define T_LEN 300
#define KS 77              // srm kernel length (alpha, tau=10, eps_tol=0.01)
#define KT 76              // effective taps j = 1..76 (srm[0] == 0 exactly)
#define KR 10              // ref kernel tail length (K_ref=11 -> 10 pending)
#define THETA_V 10.0f
#define NPB 64             // neurons per block
#define QT 80              // quarter stride: waves 0..2 do 80 outputs, wave 3 does 60
#define CH 20              // chunk of outputs per conv inner pass
#define ROWP 301           // LDS row pad: odd -> per-lane row access conflict-free

__global__ __launch_bounds__(256, 2) void spike_layer_kernel(
    const float* __restrict__ spike_in,
    const float* __restrict__ srm, int srm_len,
    const float* __restrict__ refk, int ref_len,
    float* __restrict__ out, int B)
{
    __shared__ float u_lds[NPB * ROWP];   // 77056 B -> 2 blocks/CU

    const int tid = threadIdx.x;
    const int q   = tid >> 6;             // wave index == time-quarter (uniform per wave)
    const int n   = tid & 63;             // neuron within block
    const int neuron = blockIdx.x * NPB + n;
    const bool valid = (neuron < B);

    const float* row  = spike_in + (size_t)neuron * T_LEN;
    float*       urow = &u_lds[n * ROWP];

    // srm taps (wave-uniform loads -> SGPRs). Tap 0 skipped: exactly 0.0.
    float srm_r[KS];
#pragma unroll
    for (int i = 1; i < KS; ++i) srm_r[i] = (i < srm_len) ? srm[i] : 0.0f;

    const int t0  = q * QT;                                   // 0,80,160,240
    const int nch = (q < 3) ? (QT / CH) : ((T_LEN - 3 * QT) / CH);  // 4,4,4,3

    // history window: hist[i] = x[t0 + i - KT]; tail [KT..KT+CH) = current chunk
    float hist[KT + CH];
    if (q == 0 || !valid) {
#pragma unroll
        for (int i = 0; i < KT; ++i) hist[i] = 0.0f;          // t < 0 -> no spikes
    } else {
        // pre-window = last 76 inputs of previous quarter.
        // byte offset (80q-76)*4 = 320q-304 == 0 mod 16 -> float4-aligned.
        const float4* p = (const float4*)(row + t0 - KT);
#pragma unroll
        for (int i = 0; i < KT / 4; ++i) {
            float4 v = p[i];
            hist[4*i+0] = v.x; hist[4*i+1] = v.y; hist[4*i+2] = v.z; hist[4*i+3] = v.w;
        }
    }

    // preload chunk 0 (t0 is a multiple of 20 -> 16B-aligned)
    float nxt[CH];
    if (valid) {
        const float4* p = (const float4*)(row + t0);
#pragma unroll
        for (int i = 0; i < CH / 4; ++i) {
            float4 v = p[i];
            nxt[4*i+0] = v.x; nxt[4*i+1] = v.y; nxt[4*i+2] = v.z; nxt[4*i+3] = v.w;
        }
    } else {
#pragma unroll
        for (int i = 0; i < CH; ++i) nxt[i] = 0.0f;
    }

#pragma unroll 1           // keep the ~1.6k-inst body I-cache resident
    for (int c0 = 0; c0 < nch; ++c0) {
        // install current chunk into window tail
#pragma unroll
        for (int i = 0; i < CH; ++i) hist[KT + i] = nxt[i];

        // prefetch next chunk (hidden under the 1520-FMA conv)
        if (c0 + 1 < nch && valid) {
            const float4* p = (const float4*)(row + t0 + (c0 + 1) * CH);
#pragma unroll
            for (int i = 0; i < CH / 4; ++i) {
                float4 v = p[i];
                nxt[4*i+0] = v.x; nxt[4*i+1] = v.y; nxt[4*i+2] = v.z; nxt[4*i+3] = v.w;
            }
        }

        // conv: u[t0+20*c0+c] = sum_{j=1}^{76} srm[j]*x[..-j]; 20 indep chains
        float u[CH];
#pragma unroll
        for (int c = 0; c < CH; ++c) u[c] = 0.0f;
#pragma unroll
        for (int j = 1; j < KS; ++j) {
            const float w = srm_r[j];
#pragma unroll
            for (int c = 0; c < CH; ++c)
                u[c] = fmaf(w, hist[KT + c - j], u[c]);
        }

        // u -> LDS (lanes hit distinct rows: (301n + const) mod 32 distinct -> free)
        float* up = urow + t0 + c0 * CH;
#pragma unroll
        for (int c = 0; c < CH; ++c) up[c] = u[c];

        // slide window by CH
#pragma unroll
        for (int i = 0; i < KT; ++i) hist[i] = hist[i + CH];
    }

    __syncthreads();

    // ---- scan phase: wave 0 only (lane n scans neuron n) ----
    if (q != 0 || !valid) return;

    // refractory tail: ref_kernel[1..], contributions to t+1..t+KR
    float rt[KR];
#pragma unroll
    for (int i = 0; i < KR; ++i) rt[i] = (i + 1 < ref_len) ? refk[i + 1] : 0.0f;

    // pending queue, circular: logical pend[i] lives at pend[(r+i)%KR], r = t%KR
    float pend[KR];
#pragma unroll
    for (int i = 0; i < KR; ++i) pend[i] = 0.0f;

    float* orow = out + (size_t)neuron * T_LEN;

#pragma unroll 1
    for (int cb = 0; cb < T_LEN / CH; ++cb) {
        // batch 20 independent LDS reads (conflict-free), one waitcnt
        float uv[CH];
#pragma unroll
        for (int c = 0; c < CH; ++c) uv[c] = urow[cb * CH + c];

        float so[CH];
#pragma unroll
        for (int c = 0; c < CH; ++c) {
            const int r = c % KR;      // compile-time (CH == 2*KR)
            float u_eff = uv[c] + pend[r];
            float s = (u_eff >= THETA_V) ? 1.0f : 0.0f;
#pragma unroll
            for (int i = 0; i < KR - 1; ++i)
                pend[(r + 1 + i) % KR] = fmaf(s, rt[i], pend[(r + 1 + i) % KR]);
            pend[r] = s * rt[KR - 1];  // consumed slot becomes logical tail
            so[c] = s;                 // s / TS, TS == 1
        }

        float4* op = (float4*)(orow + cb * CH);
#pragma unroll
        for (int i = 0; i < CH / 4; ++i) {
            float4 v;
            v.x = so[4*i+0]; v.y = so[4*i+1]; v.z = so[4*i+2]; v.w = so[4*i+3];
            op[i] = v;
        }
    }
}

extern "C" void kernel_launch(void* const* d_in, const int* in_sizes, int n_in,
                              void* d_out, int out_size, void* d_ws, size_t ws_size,
                              hipStream_t stream) {
    const float* spike_in = (const float*)d_in[0];
    const float* srm      = (const float*)d_in[1];
    const float* refk     = (const float*)d_in[2];
    float* out = (float*)d_out;

    int srm_len = in_sizes[1];
    int ref_len = in_sizes[2];
    int B = in_sizes[0] / T_LEN;   // 65536 neurons

    int block = 256;                       // 64 neurons x 4 time-quarters
    int grid = (B + NPB - 1) / NPB;        // 1024 blocks
    spike_layer_kernel<<<grid, block, 0, stream>>>(spike_in, srm, srm_len,
                                                   refk, ref_len, out, B);
}